// Round 7
// baseline (773.347 us; speedup 1.0000x reference)
//
#include <hip/hip_runtime.h>
#include <math.h>

#define DCOLS 4096
#define TPB   256
#define WPB   4            // waves per block; 1 wave = 1 row at a time, autonomous
#define FPL   16           // float4 loads per lane
#define VPL   64           // values per lane (whole row in one wave's VGPRs)
#define KSEL  64
#define CAP   128          // per-wave candidate cap (E in [64,128] on fast path)
#define RPW   4            // rows per wave, software-pipelined (no barriers!)

#define PIV0  2.0f         // P(z>2.0)=0.02275 -> E[cnt]=93.2, sd 9.6
#define PIV1  1.9f         // P(z>1.9)=0.02872 -> E[cnt]=117.6; used when cnt0<64

typedef float v4f __attribute__((ext_vector_type(4)));

__device__ __forceinline__ unsigned f2ord(float f) {
    unsigned b = __float_as_uint(f);
    return (b & 0x80000000u) ? ~b : (b | 0x80000000u);
}

__device__ __forceinline__ unsigned wave_sum(unsigned x) {
    #pragma unroll
    for (int o = 32; o; o >>= 1) x += __shfl_xor(x, o);
    return x;
}

__device__ __forceinline__ unsigned long long wave_max_u64(unsigned long long v) {
    unsigned lo = (unsigned)v, hi = (unsigned)(v >> 32);
    #pragma unroll
    for (int o = 32; o; o >>= 1) {
        unsigned olo = (unsigned)__shfl_xor((int)lo, o);
        unsigned ohi = (unsigned)__shfl_xor((int)hi, o);
        unsigned long long ov = ((unsigned long long)ohi << 32) | olo;
        unsigned long long cv = ((unsigned long long)hi  << 32) | lo;
        if (ov > cv) { lo = olo; hi = ohi; }
    }
    return ((unsigned long long)hi << 32) | lo;
}

__device__ __forceinline__ void load_row(const float* __restrict__ xr, int lane,
                                         float (&dst)[VPL]) {
    #pragma unroll
    for (int j = 0; j < FPL; ++j) {
        v4f v = reinterpret_cast<const v4f*>(xr)[lane + 64 * j];
        #pragma unroll
        for (int c = 0; c < 4; ++c) dst[4*j + c] = v[c];
    }
}

// Cold exact path (any distribution): wave-level, reloads its row. Rare.
__device__ __noinline__ unsigned long long fallback_tkey(const float* __restrict__ xr,
                                                         int lane) {
    unsigned u[VPL];
    #pragma unroll
    for (int j = 0; j < FPL; ++j) {
        v4f v = reinterpret_cast<const v4f*>(xr)[lane + 64 * j];
        #pragma unroll
        for (int c = 0; c < 4; ++c) u[4*j + c] = f2ord(v[c]);
    }
    unsigned long long blo = 0, bhi = 0xFFFFFFFFull;
    while (blo < bhi) {
        const unsigned mid = (unsigned)((blo + bhi + 1ull) >> 1);
        unsigned c = 0;
        #pragma unroll
        for (int i = 0; i < VPL; ++i) c += (u[i] >= mid) ? 1u : 0u;
        c = wave_sum(c);
        if (c >= KSEL) blo = mid; else bhi = mid - 1ull;
    }
    const unsigned Tu = (unsigned)blo;
    unsigned cgt = 0;
    #pragma unroll
    for (int i = 0; i < VPL; ++i) cgt += (u[i] > Tu) ? 1u : 0u;
    cgt = wave_sum(cgt);
    const unsigned remk = KSEL - cgt;                // in [1, KSEL]
    unsigned ilo = 0, ihi = DCOLS - 1;
    while (ilo < ihi) {
        const unsigned mid = (ilo + ihi) >> 1;
        unsigned c = 0;
        #pragma unroll
        for (int i = 0; i < VPL; ++i) {
            const unsigned gi = 4u*lane + 256u*(i >> 2) + (i & 3);
            c += (u[i] == Tu && gi <= mid) ? 1u : 0u;
        }
        c = wave_sum(c);
        if (c >= remk) ihi = mid; else ilo = mid + 1;
    }
    return ((unsigned long long)Tu << 32) | (unsigned)(~ilo);
}

__device__ __forceinline__ void process_row(float (&fv)[VPL],
                                            const float* __restrict__ xr,
                                            float* __restrict__ outr,
                                            int lane,
                                            unsigned long long* __restrict__ cw) {
    // ---- count above PIV0 (per-lane regs + one butterfly) ----
    unsigned lc = 0;
    #pragma unroll
    for (int i = 0; i < VPL; ++i) lc += (fv[i] > PIV0) ? 1u : 0u;
    unsigned tot = wave_sum(lc);

    float piv = PIV0; bool fast = true;
    if (tot < KSEL || tot > CAP) {          // rare (~20 rows / dataset)
        unsigned lc1 = 0;
        #pragma unroll
        for (int i = 0; i < VPL; ++i) lc1 += (fv[i] > PIV1) ? 1u : 0u;
        unsigned tot1 = wave_sum(lc1);
        if (tot1 >= KSEL && tot1 <= CAP) { piv = PIV1; lc = lc1; tot = tot1; }
        else                             { fast = false; }
    }

    unsigned long long Tkey;
    if (fast) {
        const unsigned E = tot;             // in [64, 128]
        // ---- compaction: shfl_up prefix scan -> per-lane base, no atomics ----
        unsigned incl = lc;
        #pragma unroll
        for (int o = 1; o < 64; o <<= 1) {
            unsigned n = __shfl_up(incl, o);
            if (lane >= o) incl += n;
        }
        unsigned base = incl - lc;
        #pragma unroll
        for (int i = 0; i < VPL; ++i) {
            if (fv[i] > piv) {
                const unsigned gi = 4u*lane + 256u*(i >> 2) + (i & 3);
                cw[base++] = ((unsigned long long)f2ord(fv[i]) << 32)
                           | (unsigned)(~gi);
            }
        }
        // ---- fused exact rank-(K-1): both of this lane's keys in ONE sweep ----
        const unsigned long long k0 = cw[lane];                       // lane < 64 <= E
        const bool has1 = (lane + 64u) < E;
        const unsigned long long k1 = has1 ? cw[lane + 64] : 0ull;
        unsigned r0 = 0, r1 = 0;
        for (unsigned e = 0; e < E; ++e) {
            const unsigned long long ce = cw[e];                      // broadcast
            r0 += (ce > k0) ? 1u : 0u;
            r1 += (ce > k1) ? 1u : 0u;
        }
        unsigned long long tk = 0;
        if (r0 == KSEL - 1)         tk = k0;
        if (has1 && r1 == KSEL - 1) tk = k1;
        Tkey = wave_max_u64(tk);            // broadcast the unique winner
    } else {
        Tkey = fallback_tkey(xr, lane);
    }

    // ---- decode threshold (value, tie-index) ----
    const unsigned hi32 = (unsigned)(Tkey >> 32);
    const unsigned Ti   = ~((unsigned)Tkey);
    const unsigned tb   = (hi32 & 0x80000000u) ? (hi32 & 0x7FFFFFFFu) : ~hi32;
    const float    Tf   = __uint_as_float(tb);

    // ---- emit: sigmoid for selected, 0 otherwise; coalesced float4 stores ----
    #pragma unroll
    for (int j = 0; j < FPL; ++j) {
        v4f o;
        #pragma unroll
        for (int c = 0; c < 4; ++c) {
            const int i = 4*j + c;
            const unsigned gi = 4u*lane + 256u*j + c;
            const bool inc = (fv[i] > Tf) || (fv[i] == Tf && gi <= Ti);
            const float e  = __expf(-fv[i]);
            o[c] = inc ? __builtin_amdgcn_rcpf(1.0f + e) : 0.0f;
        }
        reinterpret_cast<v4f*>(outr)[lane + 64 * j] = o;
    }
}

__global__ __launch_bounds__(TPB, 3) void topk_sigmoid_kernel(
    const float* __restrict__ x, float* __restrict__ out)
{
    const int t    = threadIdx.x;
    const int w    = t >> 6;
    const int lane = t & 63;
    const size_t row0 = ((size_t)blockIdx.x * WPB + w) * RPW;

    __shared__ unsigned long long cand[WPB][CAP];   // private per-wave segment
    unsigned long long* cw = cand[w];

    float A[VPL], B[VPL];

    // software pipeline over RPW consecutive rows — NO barriers anywhere,
    // so prefetched loads stay in flight across select/emit (no vmcnt(0) drain)
    load_row(x + row0 * DCOLS, lane, A);
    #pragma unroll
    for (int rp = 0; rp < RPW / 2; ++rp) {
        const size_t r0 = row0 + 2*rp;
        // prefetch odd row, then process even row
        load_row(x + (r0 + 1) * DCOLS, lane, B);
        process_row(A, x + r0 * DCOLS, out + r0 * DCOLS, lane, cw);
        // prefetch next even row, then process odd row
        if (2*rp + 2 < RPW)
            load_row(x + (r0 + 2) * DCOLS, lane, A);
        process_row(B, x + (r0 + 1) * DCOLS, out + (r0 + 1) * DCOLS, lane, cw);
    }
}

extern "C" void kernel_launch(void* const* d_in, const int* in_sizes, int n_in,
                              void* d_out, int out_size, void* d_ws, size_t ws_size,
                              hipStream_t stream) {
    const float* x  = (const float*)d_in[0];
    float* out      = (float*)d_out;
    const int nrows = in_sizes[0] / DCOLS;           // 16384
    const int grid  = nrows / (WPB * RPW);           // 1024 blocks
    topk_sigmoid_kernel<<<grid, TPB, 0, stream>>>(x, out);
}

// Round 8
// 461.885 us; speedup vs baseline: 1.6743x; 1.6743x over previous
//
#include <hip/hip_runtime.h>
#include <math.h>

#define DCOLS 4096
#define TPB   256
#define WPB   4            // waves per block; 1 wave = 1 row, fully autonomous
#define FPL   16           // float4 chunks per lane (64 lanes x 16 x 4 = 4096)
#define KSEL  64
#define CAP   160          // per-wave candidate cap; P(cnt>2.0 > 160) ~ 7 sigma

#define PIV0  2.0f         // P(z>2.0)=0.02275 -> E[cnt]=93.2, sd 9.6
#define PIV1  1.9f         // P(z>1.9)=0.02872 -> E[cnt]=117.6; backup when cnt0<64

typedef float v4f __attribute__((ext_vector_type(4)));

__device__ __forceinline__ unsigned f2ord(float f) {
    unsigned b = __float_as_uint(f);
    return (b & 0x80000000u) ? ~b : (b | 0x80000000u);
}

__device__ __forceinline__ unsigned wave_sum(unsigned x) {
    #pragma unroll
    for (int o = 32; o; o >>= 1) x += __shfl_xor(x, o);
    return x;
}

__device__ __forceinline__ unsigned long long wave_max_u64(unsigned long long v) {
    unsigned lo = (unsigned)v, hi = (unsigned)(v >> 32);
    #pragma unroll
    for (int o = 32; o; o >>= 1) {
        unsigned olo = (unsigned)__shfl_xor((int)lo, o);
        unsigned ohi = (unsigned)__shfl_xor((int)hi, o);
        unsigned long long ov = ((unsigned long long)ohi << 32) | olo;
        unsigned long long cv = ((unsigned long long)hi  << 32) | lo;
        if (ov > cv) { lo = olo; hi = ohi; }
    }
    return ((unsigned long long)hi << 32) | lo;
}

// Stream the row once; compact keys of elements > piv into this wave's LDS
// segment (ballot + mbcnt positions, zero atomics, nothing retained in VGPRs).
// Optionally counts elements > PIV1 as a backup. Returns wave-uniform total.
__device__ __forceinline__ unsigned compact_pass(const v4f* __restrict__ xv, int lane,
                                                 float piv,
                                                 unsigned long long* __restrict__ cw,
                                                 unsigned* cnt1) {
    unsigned wb = 0;
    v4f va = xv[lane];                       // 2-deep rotation: load j+1, process j
    #pragma unroll
    for (int j = 0; j < FPL; ++j) {
        v4f vb;
        if (j + 1 < FPL) vb = xv[lane + 64 * (j + 1)];
        #pragma unroll
        for (int c = 0; c < 4; ++c) {
            const float f = va[c];
            if (cnt1) *cnt1 += (f > PIV1) ? 1u : 0u;
            const bool pred = f > piv;
            const unsigned long long m = __ballot(pred);
            if (pred) {
                const unsigned below = __builtin_amdgcn_mbcnt_hi(
                    (unsigned)(m >> 32),
                    __builtin_amdgcn_mbcnt_lo((unsigned)m, 0u));
                const unsigned pos = wb + below;
                const unsigned gi  = 4u * lane + 256u * j + c;
                if (pos < CAP)               // overflow-guard: protects neighbors
                    cw[pos] = ((unsigned long long)f2ord(f) << 32)
                            | (unsigned)(~gi);
            }
            wb += (unsigned)__popcll(m);
        }
        va = vb;
    }
    return wb;
}

// Exact rank-(K-1) among E in [64, CAP] keys: each lane ranks its <=3 keys in
// one broadcast sweep of the list; unique winner broadcast via shfl-max.
__device__ __forceinline__ unsigned long long rank_select(
        const unsigned long long* __restrict__ cw, unsigned E, int lane) {
    const unsigned long long k0 = cw[lane];            // lane < 64 <= E
    const bool h1 = (lane + 64u)  < E;
    const bool h2 = (lane + 128u) < E;
    const unsigned long long k1 = h1 ? cw[lane + 64]  : 0ull;
    const unsigned long long k2 = h2 ? cw[lane + 128] : 0ull;
    unsigned r0 = 0, r1 = 0, r2 = 0;
    for (unsigned e = 0; e < E; ++e) {
        const unsigned long long ce = cw[e];           // broadcast, conflict-free
        r0 += (ce > k0) ? 1u : 0u;
        r1 += (ce > k1) ? 1u : 0u;
        r2 += (ce > k2) ? 1u : 0u;
    }
    unsigned long long tk = 0;
    if (r0 == KSEL - 1)       tk = k0;
    if (h1 && r1 == KSEL - 1) tk = k1;
    if (h2 && r2 == KSEL - 1) tk = k2;
    return wave_max_u64(tk);
}

// Cold exact path (any distribution): streaming binary search, ~12 VGPRs,
// reloads the (L2-hot) row per iteration. Ultra-rare on N(0,1) data.
__device__ __noinline__ unsigned long long fallback_stream(
        const v4f* __restrict__ xv, int lane) {
    unsigned long long blo = 0, bhi = 0xFFFFFFFFull;
    while (blo < bhi) {
        const unsigned mid = (unsigned)((blo + bhi + 1ull) >> 1);
        unsigned c = 0;
        for (int j = 0; j < FPL; ++j) {
            v4f v = xv[lane + 64 * j];
            #pragma unroll
            for (int cc = 0; cc < 4; ++cc) c += (f2ord(v[cc]) >= mid) ? 1u : 0u;
        }
        c = wave_sum(c);
        if (c >= KSEL) blo = mid; else bhi = mid - 1ull;
    }
    const unsigned Tu = (unsigned)blo;
    unsigned cgt = 0;
    for (int j = 0; j < FPL; ++j) {
        v4f v = xv[lane + 64 * j];
        #pragma unroll
        for (int cc = 0; cc < 4; ++cc) cgt += (f2ord(v[cc]) > Tu) ? 1u : 0u;
    }
    cgt = wave_sum(cgt);
    const unsigned remk = KSEL - cgt;                  // in [1, KSEL]
    unsigned ilo = 0, ihi = DCOLS - 1;
    while (ilo < ihi) {
        const unsigned mid = (ilo + ihi) >> 1;
        unsigned c = 0;
        for (int j = 0; j < FPL; ++j) {
            v4f v = xv[lane + 64 * j];
            #pragma unroll
            for (int cc = 0; cc < 4; ++cc) {
                const unsigned gi = 4u * lane + 256u * j + cc;
                c += (f2ord(v[cc]) == Tu && gi <= mid) ? 1u : 0u;
            }
        }
        c = wave_sum(c);
        if (c >= remk) ihi = mid; else ilo = mid + 1;
    }
    return ((unsigned long long)Tu << 32) | (unsigned)(~ilo);
}

__global__ __launch_bounds__(TPB, 6) void topk_sigmoid_kernel(
    const float* __restrict__ x, float* __restrict__ out)
{
    const int t    = threadIdx.x;
    const int w    = t >> 6;
    const int lane = t & 63;
    const size_t row = (size_t)blockIdx.x * WPB + w;
    const v4f* xv = reinterpret_cast<const v4f*>(x   + row * DCOLS);
    v4f*       ov = reinterpret_cast<v4f*>(      out + row * DCOLS);

    __shared__ unsigned long long cand[WPB][CAP];   // private per-wave segments
    unsigned long long* cw = cand[w];

    // ---- pass A: stream row, compact >PIV0 candidates into LDS ----
    unsigned cnt1 = 0;
    const unsigned tot0 = compact_pass(xv, lane, PIV0, cw, &cnt1);

    unsigned long long Tkey;
    if (tot0 >= KSEL && tot0 <= CAP) {
        Tkey = rank_select(cw, tot0, lane);
    } else {
        const unsigned tot1 = wave_sum(cnt1);       // backup pivot count
        if (tot1 >= KSEL && tot1 <= CAP) {          // ~21 rows / dataset
            const unsigned e1 = compact_pass(xv, lane, PIV1, cw, nullptr);
            Tkey = rank_select(cw, e1, lane);
        } else {                                    // essentially never (exact)
            Tkey = fallback_stream(xv, lane);
        }
    }

    // ---- decode threshold (value, tie-index) ----
    const unsigned hi32 = (unsigned)(Tkey >> 32);
    const unsigned Ti   = ~((unsigned)Tkey);
    const unsigned tb   = (hi32 & 0x80000000u) ? (hi32 & 0x7FFFFFFFu) : ~hi32;
    const float    Tf   = __uint_as_float(tb);

    // ---- pass B: re-read row (L2-hot), emit sigmoid/0, coalesced stores ----
    #pragma unroll
    for (int j = 0; j < FPL; ++j) {
        const v4f v = xv[lane + 64 * j];
        v4f o;
        #pragma unroll
        for (int c = 0; c < 4; ++c) {
            const unsigned gi = 4u * lane + 256u * j + c;
            const bool inc = (v[c] > Tf) || (v[c] == Tf && gi <= Ti);
            const float e  = __expf(-v[c]);
            o[c] = inc ? __builtin_amdgcn_rcpf(1.0f + e) : 0.0f;
        }
        ov[lane + 64 * j] = o;
    }
}

extern "C" void kernel_launch(void* const* d_in, const int* in_sizes, int n_in,
                              void* d_out, int out_size, void* d_ws, size_t ws_size,
                              hipStream_t stream) {
    const float* x  = (const float*)d_in[0];
    float* out      = (float*)d_out;
    const int nrows = in_sizes[0] / DCOLS;           // 16384
    topk_sigmoid_kernel<<<nrows / WPB, TPB, 0, stream>>>(x, out);
}